// Round 1
// baseline (2748.320 us; speedup 1.0000x reference)
//
#include <hip/hip_runtime.h>

typedef __attribute__((ext_vector_type(8))) short short8;
typedef __attribute__((ext_vector_type(4))) float f32x4;
typedef __attribute__((ext_vector_type(4))) unsigned short ushort4v;

#define AS1(p) ((const __attribute__((address_space(1))) void*)(p))
#define AS3(p) ((__attribute__((address_space(3))) void*)(p))

__device__ __forceinline__ float bf2f(unsigned short v) {
    union { unsigned u; float f; } c; c.u = ((unsigned)v) << 16; return c.f;
}
__device__ __forceinline__ unsigned short f2bf(float f) {
    union { float f; unsigned u; } c; c.f = f;
    unsigned u = c.u;
    return (unsigned short)((u + 0x7FFFu + ((u >> 16) & 1u)) >> 16);
}

// ---------------------------------------------------------------------------
// fp32 [R][C] -> bf16 [C][R] transpose+convert (weights)
// ---------------------------------------------------------------------------
__global__ __launch_bounds__(256) void transpose_cvt(
    const float* __restrict__ in, unsigned short* __restrict__ out, int R, int C)
{
    __shared__ float tile[32][33];
    int bx = blockIdx.x * 32;            // C dim
    int by = blockIdx.y * 32;            // R dim
    int tx = threadIdx.x & 31, ty = threadIdx.x >> 5;   // 32 x 8
    #pragma unroll
    for (int i = ty; i < 32; i += 8)
        tile[i][tx] = in[(size_t)(by + i) * C + bx + tx];
    __syncthreads();
    #pragma unroll
    for (int i = ty; i < 32; i += 8)
        out[(size_t)(bx + i) * R + by + tx] = f2bf(tile[tx][i]);
}

// ---------------------------------------------------------------------------
// fp32 -> bf16 elementwise (x for layer 0)
// ---------------------------------------------------------------------------
__global__ __launch_bounds__(256) void cvt_f32_bf16(
    const float* __restrict__ in, unsigned short* __restrict__ out, int n)
{
    int i4 = (blockIdx.x * 256 + threadIdx.x) * 4;
    if (i4 < n) {
        f32x4 v = *(const f32x4*)(in + i4);
        ushort4v o = { f2bf(v[0]), f2bf(v[1]), f2bf(v[2]), f2bf(v[3]) };
        *(ushort4v*)(out + i4) = o;
    }
}

// ---------------------------------------------------------------------------
// GEMM: C[M][N] = A[M][K] @ Bt[N][K]^T + bias, m97-style.
// MODE 0: fp32 out + bias0.  MODE 1: bf16 relu(x+bias0).  MODE 2: qkv scatter.
// ---------------------------------------------------------------------------
template <int MODE>
__global__ __launch_bounds__(256)
void gemm_bt(const unsigned short* __restrict__ A,
             const unsigned short* __restrict__ Bt,
             const float* __restrict__ bias0,
             const float* __restrict__ bias1,
             const float* __restrict__ bias2,
             float* __restrict__ outF,
             unsigned short* __restrict__ outB,
             int M, int N, int K)
{
    __shared__ __align__(16) unsigned short As[128 * 32];   // [m][k]
    __shared__ __align__(16) unsigned short Bs[128 * 32];   // [n][k]

    int tid = threadIdx.x;
    int wave = tid >> 6, lane = tid & 63;
    int ml = lane & 15, quad = lane >> 4;
    int m0 = blockIdx.y * 128, n0 = blockIdx.x * 128;
    int wm = (wave >> 1) * 64, wn = (wave & 1) * 64;

    f32x4 acc[4][4];
    #pragma unroll
    for (int i = 0; i < 4; i++)
        #pragma unroll
        for (int j = 0; j < 4; j++)
            #pragma unroll
            for (int r = 0; r < 4; r++) acc[i][j][r] = 0.0f;

    int srow = lane >> 2, skp = (lane & 3) * 8;

    for (int k0 = 0; k0 < K; k0 += 32) {
        #pragma unroll
        for (int c2 = 0; c2 < 2; c2++) {
            int c = wave + c2 * 4;   // chunk 0..7; 64 lanes x 16B = 512 elems
            const unsigned short* ga = A + (size_t)(m0 + c * 16 + srow) * K + (k0 + skp);
            __builtin_amdgcn_global_load_lds(AS1(ga), AS3(As + c * 512), 16, 0, 0);
            const unsigned short* gb = Bt + (size_t)(n0 + c * 16 + srow) * K + (k0 + skp);
            __builtin_amdgcn_global_load_lds(AS1(gb), AS3(Bs + c * 512), 16, 0, 0);
        }
        __syncthreads();

        short8 af[4], bfr[4];
        #pragma unroll
        for (int i = 0; i < 4; i++)
            af[i] = *(const short8*)(As + (wm + i * 16 + ml) * 32 + quad * 8);
        #pragma unroll
        for (int j = 0; j < 4; j++)
            bfr[j] = *(const short8*)(Bs + (wn + j * 16 + ml) * 32 + quad * 8);
        #pragma unroll
        for (int i = 0; i < 4; i++)
            #pragma unroll
            for (int j = 0; j < 4; j++)
                acc[i][j] = __builtin_amdgcn_mfma_f32_16x16x32_bf16(af[i], bfr[j], acc[i][j], 0, 0, 0);
        __syncthreads();
    }

    size_t Ns = (size_t)N;
    #pragma unroll
    for (int j = 0; j < 4; j++) {
        int ng = n0 + wn + j * 16 + ml;
        float bv;
        if (MODE == 2) {
            int which = ng >> 10;
            const float* bp = (which == 0) ? bias0 : ((which == 1) ? bias1 : bias2);
            bv = bp[ng & 1023];
        } else {
            bv = bias0[ng];
        }
        #pragma unroll
        for (int i = 0; i < 4; i++) {
            #pragma unroll
            for (int r = 0; r < 4; r++) {
                int mg = m0 + wm + i * 16 + quad * 4 + r;
                float v = acc[i][j][r] + bv;
                if (MODE == 0) {
                    outF[(size_t)mg * Ns + ng] = v;
                } else if (MODE == 1) {
                    outB[(size_t)mg * Ns + ng] = f2bf(fmaxf(v, 0.0f));
                } else {
                    int which = ng >> 10, wi = ng & 1023;
                    int h = wi >> 6, d = wi & 63;
                    int b = mg >> 10, s = mg & 1023;
                    outB[(size_t)which * 4194304 +
                         ((size_t)(b * 16 + h) * 1024 + s) * 64 + d] = f2bf(v);
                }
            }
        }
    }
}

// ---------------------------------------------------------------------------
// qEc[b,h,s,n] = ( q[b,h,s,:] . Erel[n,:] + Brel[h,n] ) * scale
// ---------------------------------------------------------------------------
__global__ __launch_bounds__(256) void qe_kernel(
    const unsigned short* __restrict__ q,     // [B,H,S,64] bf16
    const float* __restrict__ Erel,           // [33][64]
    const float* __restrict__ Brel,           // [16][33]
    float* __restrict__ out)                  // [B,H,S,33]
{
    int idx = blockIdx.x * 256 + threadIdx.x;
    if (idx >= 2162688) return;
    int n = idx % 33;
    int row = idx / 33;
    const short8* qv = (const short8*)(q + (size_t)row * 64);
    float s = 0.0f;
    #pragma unroll
    for (int c = 0; c < 8; c++) {
        short8 qq = qv[c];
        const float* e = Erel + n * 64 + c * 8;
        #pragma unroll
        for (int j = 0; j < 8; j++) s += bf2f((unsigned short)qq[j]) * e[j];
    }
    int h = (row >> 10) & 15;
    out[idx] = (s + Brel[h * 33 + n]) * 0.125f;
}

// ---------------------------------------------------------------------------
// Flash attention with bucket-gathered additive scores.
// One block = (b, h, 64-row q tile). 4 waves, online softmax.
// ---------------------------------------------------------------------------
__global__ __launch_bounds__(256)
void attn_kernel(const unsigned short* __restrict__ Q,   // [B,H,S,64]
                 const unsigned short* __restrict__ Kin,
                 const unsigned short* __restrict__ V,
                 const int* __restrict__ rid,             // [S,S]
                 const float* __restrict__ qEc,           // [B,H,S,33] prescaled incl Brel
                 unsigned short* __restrict__ outp)       // [B,S,H*64]
{
    const float scale = 0.125f;
    int bid = blockIdx.x;
    int qt = bid & 15, h = (bid >> 4) & 15, b = bid >> 8;
    int q0 = qt * 64;
    size_t bh = (size_t)(b * 16 + h);
    const unsigned short* Qp = Q + (bh * 1024 + q0) * 64;
    const unsigned short* Kp = Kin + bh * 65536;
    const unsigned short* Vp = V + bh * 65536;
    const float* qEp = qEc + (bh * 1024 + q0) * 33;

    __shared__ __align__(16) unsigned short Qs[64 * 80];
    __shared__ __align__(16) unsigned short Ks[64 * 80];
    __shared__ __align__(16) unsigned short VT[64 * 80];   // [d][k]
    __shared__ __align__(16) unsigned short Ps[64 * 80];
    __shared__ float comb[64 * 33];

    int tid = threadIdx.x;
    int wave = tid >> 6, lane = tid & 63;
    int ml = lane & 15, quad = lane >> 4;

    {   // stage Q (stride 80)
        int r = tid >> 2, c = (tid & 3) * 16;
        short8 v0 = *(const short8*)(Qp + r * 64 + c);
        short8 v1 = *(const short8*)(Qp + r * 64 + c + 8);
        *(short8*)(Qs + r * 80 + c) = v0;
        *(short8*)(Qs + r * 80 + c + 8) = v1;
    }
    for (int i = tid; i < 2112; i += 256) comb[i] = qEp[i];
    __syncthreads();

    short8 aq0 = *(const short8*)(Qs + (wave * 16 + ml) * 80 + quad * 8);
    short8 aq1 = *(const short8*)(Qs + (wave * 16 + ml) * 80 + 32 + quad * 8);

    float m_st[4], l_st[4];
    f32x4 o_acc[4];
    #pragma unroll
    for (int r = 0; r < 4; r++) { m_st[r] = -1e30f; l_st[r] = 0.0f; }
    #pragma unroll
    for (int j = 0; j < 4; j++)
        #pragma unroll
        for (int r = 0; r < 4; r++) o_acc[j][r] = 0.0f;

    for (int kt = 0; kt < 16; kt++) {
        {   // stage K tile [k][d] and V tile transposed [d][k]
            int r = tid >> 2, c = (tid & 3) * 16;
            short8 k0 = *(const short8*)(Kp + (size_t)(kt * 64 + r) * 64 + c);
            short8 k1 = *(const short8*)(Kp + (size_t)(kt * 64 + r) * 64 + c + 8);
            *(short8*)(Ks + r * 80 + c) = k0;
            *(short8*)(Ks + r * 80 + c + 8) = k1;
            short8 v0 = *(const short8*)(Vp + (size_t)(kt * 64 + r) * 64 + c);
            short8 v1 = *(const short8*)(Vp + (size_t)(kt * 64 + r) * 64 + c + 8);
            unsigned short tmp[16];
            *(short8*)tmp = v0; *(short8*)(tmp + 8) = v1;
            #pragma unroll
            for (int d2 = 0; d2 < 16; d2++) VT[(c + d2) * 80 + r] = tmp[d2];
        }
        __syncthreads();

        f32x4 s_acc[4];
        #pragma unroll
        for (int j = 0; j < 4; j++)
            #pragma unroll
            for (int r = 0; r < 4; r++) s_acc[j][r] = 0.0f;
        #pragma unroll
        for (int j = 0; j < 4; j++) {
            short8 bk0 = *(const short8*)(Ks + (j * 16 + ml) * 80 + quad * 8);
            short8 bk1 = *(const short8*)(Ks + (j * 16 + ml) * 80 + 32 + quad * 8);
            s_acc[j] = __builtin_amdgcn_mfma_f32_16x16x32_bf16(aq0, bk0, s_acc[j], 0, 0, 0);
            s_acc[j] = __builtin_amdgcn_mfma_f32_16x16x32_bf16(aq1, bk1, s_acc[j], 0, 0, 0);
        }

        // add gathered rel scores; online softmax
        float sv[4][4];
        #pragma unroll
        for (int r = 0; r < 4; r++) {
            int qrow = wave * 16 + quad * 4 + r;
            int gq = q0 + qrow;
            #pragma unroll
            for (int j = 0; j < 4; j++) {
                int kcol = j * 16 + ml;
                int bucket = rid[(size_t)gq * 1024 + kt * 64 + kcol];
                sv[j][r] = s_acc[j][r] * scale + comb[qrow * 33 + bucket];
            }
        }
        #pragma unroll
        for (int r = 0; r < 4; r++) {
            int qrow = wave * 16 + quad * 4 + r;
            float mx = fmaxf(fmaxf(sv[0][r], sv[1][r]), fmaxf(sv[2][r], sv[3][r]));
            mx = fmaxf(mx, __shfl_xor(mx, 1, 64));
            mx = fmaxf(mx, __shfl_xor(mx, 2, 64));
            mx = fmaxf(mx, __shfl_xor(mx, 4, 64));
            mx = fmaxf(mx, __shfl_xor(mx, 8, 64));
            float mnew = fmaxf(m_st[r], mx);
            float alpha = __expf(m_st[r] - mnew);
            float ps = 0.0f;
            #pragma unroll
            for (int j = 0; j < 4; j++) {
                float pv = __expf(sv[j][r] - mnew);
                ps += pv;
                Ps[qrow * 80 + j * 16 + ml] = f2bf(pv);
            }
            ps += __shfl_xor(ps, 1, 64);
            ps += __shfl_xor(ps, 2, 64);
            ps += __shfl_xor(ps, 4, 64);
            ps += __shfl_xor(ps, 8, 64);
            l_st[r] = l_st[r] * alpha + ps;
            m_st[r] = mnew;
            #pragma unroll
            for (int j = 0; j < 4; j++) o_acc[j][r] *= alpha;
        }
        __syncthreads();

        short8 ap0 = *(const short8*)(Ps + (wave * 16 + ml) * 80 + quad * 8);
        short8 ap1 = *(const short8*)(Ps + (wave * 16 + ml) * 80 + 32 + quad * 8);
        #pragma unroll
        for (int j = 0; j < 4; j++) {
            short8 bv0 = *(const short8*)(VT + (j * 16 + ml) * 80 + quad * 8);
            short8 bv1 = *(const short8*)(VT + (j * 16 + ml) * 80 + 32 + quad * 8);
            o_acc[j] = __builtin_amdgcn_mfma_f32_16x16x32_bf16(ap0, bv0, o_acc[j], 0, 0, 0);
            o_acc[j] = __builtin_amdgcn_mfma_f32_16x16x32_bf16(ap1, bv1, o_acc[j], 0, 0, 0);
        }
        __syncthreads();
    }

    #pragma unroll
    for (int r = 0; r < 4; r++) {
        int qrow = wave * 16 + quad * 4 + r;
        float invl = 1.0f / l_st[r];
        size_t base = ((size_t)(b * 1024 + q0 + qrow)) * 1024 + h * 64;
        #pragma unroll
        for (int j = 0; j < 4; j++)
            outp[base + j * 16 + ml] = f2bf(o_acc[j][r] * invl);
    }
}

// ---------------------------------------------------------------------------
// LayerNorm( a + b ) * g + be  -> fp32 out (+ optional bf16 out). D = 1024.
// ---------------------------------------------------------------------------
__global__ __launch_bounds__(256) void ln_kernel(
    const float* __restrict__ a, const float* __restrict__ b,
    const float* __restrict__ g, const float* __restrict__ be,
    float* __restrict__ outF, unsigned short* __restrict__ outB)
{
    int row = blockIdx.x, tid = threadIdx.x;
    int wave = tid >> 6, lane = tid & 63;
    f32x4 xa = *(const f32x4*)(a + (size_t)row * 1024 + tid * 4);
    f32x4 xb = *(const f32x4*)(b + (size_t)row * 1024 + tid * 4);
    f32x4 x;
    #pragma unroll
    for (int i = 0; i < 4; i++) x[i] = xa[i] + xb[i];
    float s1 = x[0] + x[1] + x[2] + x[3];
    float s2 = x[0]*x[0] + x[1]*x[1] + x[2]*x[2] + x[3]*x[3];
    #pragma unroll
    for (int off = 1; off < 64; off <<= 1) {
        s1 += __shfl_xor(s1, off, 64);
        s2 += __shfl_xor(s2, off, 64);
    }
    __shared__ float r1[4], r2[4];
    if (lane == 0) { r1[wave] = s1; r2[wave] = s2; }
    __syncthreads();
    s1 = r1[0] + r1[1] + r1[2] + r1[3];
    s2 = r2[0] + r2[1] + r2[2] + r2[3];
    float mean = s1 * (1.0f / 1024.0f);
    float var  = s2 * (1.0f / 1024.0f) - mean * mean;
    float inv  = rsqrtf(var + 1e-6f);
    f32x4 gg = *(const f32x4*)(g + tid * 4);
    f32x4 bb = *(const f32x4*)(be + tid * 4);
    f32x4 o;
    #pragma unroll
    for (int i = 0; i < 4; i++) o[i] = (x[i] - mean) * inv * gg[i] + bb[i];
    *(f32x4*)(outF + (size_t)row * 1024 + tid * 4) = o;
    if (outB != nullptr) {
        ushort4v ov = { f2bf(o[0]), f2bf(o[1]), f2bf(o[2]), f2bf(o[3]) };
        *(ushort4v*)(outB + (size_t)row * 1024 + tid * 4) = ov;
    }
}

// ---------------------------------------------------------------------------
extern "C" void kernel_launch(void* const* d_in, const int* in_sizes, int n_in,
                              void* d_out, int out_size, void* d_ws, size_t ws_size,
                              hipStream_t stream)
{
    const float* x_in = (const float*)d_in[0];
    const int*   rid  = (const int*)d_in[1];
    const float* Wq = (const float*)d_in[2];  const float* bq = (const float*)d_in[3];
    const float* Wk = (const float*)d_in[4];  const float* bk = (const float*)d_in[5];
    const float* Wv = (const float*)d_in[6];  const float* bv = (const float*)d_in[7];
    const float* Wo = (const float*)d_in[8];  const float* bo = (const float*)d_in[9];
    const float* Erel = (const float*)d_in[10];
    const float* Brel = (const float*)d_in[11];
    const float* g1 = (const float*)d_in[12]; const float* be1 = (const float*)d_in[13];
    const float* g2 = (const float*)d_in[14]; const float* be2 = (const float*)d_in[15];
    const float* W1 = (const float*)d_in[16]; const float* b1 = (const float*)d_in[17];
    const float* W2 = (const float*)d_in[18]; const float* b2 = (const float*)d_in[19];

    char* p = (char*)d_ws;
    auto alloc = [&](size_t bytes) {
        char* r = p; p += (bytes + 255) & ~(size_t)255; return (void*)r;
    };
    unsigned short* wqkv_t = (unsigned short*)alloc(3ull * 1024 * 1024 * 2); // [3072][1024]
    unsigned short* wo_t   = (unsigned short*)alloc(1024ull * 1024 * 2);     // [1024][1024]
    unsigned short* w1_t   = (unsigned short*)alloc(4096ull * 1024 * 2);     // [4096][1024]
    unsigned short* w2_t   = (unsigned short*)alloc(1024ull * 4096 * 2);     // [1024][4096]
    float*          xf     = (float*)alloc(4096ull * 1024 * 4);
    unsigned short* xb     = (unsigned short*)alloc(4096ull * 1024 * 2);
    unsigned short* qkvb   = (unsigned short*)alloc(3ull * 4194304 * 2);     // q|k|v [B,H,S,64]
    unsigned short* attnb  = (unsigned short*)alloc(4096ull * 1024 * 2);     // contiguous after qkvb
    float*          qEcb   = (float*)alloc(2162688ull * 4);                  // [B,H,S,33]
    float*          proj   = (float*)alloc(4096ull * 1024 * 4);              // also ff2
    float*          ffin   = (float*)alloc(4096ull * 1024 * 4);
    unsigned short* ffinb  = (unsigned short*)alloc(4096ull * 1024 * 2);
    unsigned short* hb     = qkvb;   // 32MB reuse (qkvb+attnb dead by FFN1)

    cvt_f32_bf16<<<4096, 256, 0, stream>>>(x_in, xb, 4194304);

    const float* xcur = x_in;
    for (int l = 0; l < 6; l++) {
        transpose_cvt<<<dim3(32, 32), 256, 0, stream>>>(Wq + (size_t)l * 1048576, wqkv_t,           1024, 1024);
        transpose_cvt<<<dim3(32, 32), 256, 0, stream>>>(Wk + (size_t)l * 1048576, wqkv_t + 1048576, 1024, 1024);
        transpose_cvt<<<dim3(32, 32), 256, 0, stream>>>(Wv + (size_t)l * 1048576, wqkv_t + 2097152, 1024, 1024);
        transpose_cvt<<<dim3(32, 32), 256, 0, stream>>>(Wo + (size_t)l * 1048576, wo_t,             1024, 1024);
        transpose_cvt<<<dim3(128, 32), 256, 0, stream>>>(W1 + (size_t)l * 4194304, w1_t, 1024, 4096);
        transpose_cvt<<<dim3(32, 128), 256, 0, stream>>>(W2 + (size_t)l * 4194304, w2_t, 4096, 1024);

        // QKV fused: [4096,1024] @ [1024,3072] -> scatter to [3][B,H,S,64] bf16
        gemm_bt<2><<<dim3(24, 32), 256, 0, stream>>>(
            xb, wqkv_t, bq + l * 1024, bk + l * 1024, bv + l * 1024,
            nullptr, qkvb, 4096, 3072, 1024);

        qe_kernel<<<8448, 256, 0, stream>>>(qkvb, Erel + l * 2112, Brel + l * 528, qEcb);

        attn_kernel<<<1024, 256, 0, stream>>>(
            qkvb, qkvb + 4194304, qkvb + 8388608, rid, qEcb, attnb);

        // O projection -> fp32 proj
        gemm_bt<0><<<dim3(8, 32), 256, 0, stream>>>(
            attnb, wo_t, bo + l * 1024, nullptr, nullptr,
            proj, nullptr, 4096, 1024, 1024);

        // ff_in = LN(x + proj)
        ln_kernel<<<4096, 256, 0, stream>>>(
            xcur, proj, g1 + l * 1024, be1 + l * 1024, ffin, ffinb);

        // FFN1: relu(ffin @ W1 + b1) -> bf16 hb
        gemm_bt<1><<<dim3(32, 32), 256, 0, stream>>>(
            ffinb, w1_t, b1 + l * 4096, nullptr, nullptr,
            nullptr, hb, 4096, 4096, 1024);

        // FFN2: hb @ W2 + b2 -> fp32 (reuse proj)
        gemm_bt<0><<<dim3(8, 32), 256, 0, stream>>>(
            hb, w2_t, b2 + l * 1024, nullptr, nullptr,
            proj, nullptr, 4096, 1024, 4096);

        // x_next = LN(ffin + ff2)
        float* lnout = (l == 5) ? (float*)d_out : xf;
        unsigned short* lnoutb = (l == 5) ? nullptr : xb;
        ln_kernel<<<4096, 256, 0, stream>>>(
            ffin, proj, g2 + l * 1024, be2 + l * 1024, lnout, lnoutb);
        xcur = xf;
    }
}